// Round 4
// baseline (415.920 us; speedup 1.0000x reference)
//
#include <hip/hip_runtime.h>
#include <hip/hip_bf16.h>
#include <cstdint>
#include <cstddef>

#define BB 2
#define SS 2048
#define EE 1024
#define HH 16
#define MM (BB*SS)   // 4096

typedef __bf16 bf16;
typedef __bf16 bf16x2 __attribute__((ext_vector_type(2)));
typedef __bf16 bf16x8 __attribute__((ext_vector_type(8)));
typedef float f32x4 __attribute__((ext_vector_type(4)));

#define GLD16(gsrc, ldst) \
  __builtin_amdgcn_global_load_lds((const __attribute__((address_space(1))) void*)(gsrc), \
                                   (__attribute__((address_space(3))) void*)(ldst), 16, 0, 0)

// ---------------- f32 -> bf16 convert ----------------
__global__ __launch_bounds__(256) void cvt_f32_bf16(const float* __restrict__ src,
                                                    bf16* __restrict__ dst, int n) {
    int i = (blockIdx.x * 256 + threadIdx.x) * 8;
    if (i >= n) return;
    float4 a = *(const float4*)(src + i);
    float4 b = *(const float4*)(src + i + 4);
    bf16 o[8] = {(bf16)a.x,(bf16)a.y,(bf16)a.z,(bf16)a.w,
                 (bf16)b.x,(bf16)b.y,(bf16)b.z,(bf16)b.w};
    *(uint4*)(dst + i) = *(uint4*)o;
}

// convert the 4 weight matrices (each 1M elems) in one launch
__global__ __launch_bounds__(256) void cvt4(const float* __restrict__ a, const float* __restrict__ b,
                                            const float* __restrict__ c, const float* __restrict__ d,
                                            bf16* __restrict__ oa, bf16* __restrict__ ob,
                                            bf16* __restrict__ oc, bf16* __restrict__ od) {
    int sel = blockIdx.y;
    const float* s = sel == 0 ? a : sel == 1 ? b : sel == 2 ? c : d;
    bf16* o       = sel == 0 ? oa : sel == 1 ? ob : sel == 2 ? oc : od;
    int i = (blockIdx.x * 256 + threadIdx.x) * 8;
    float4 x = *(const float4*)(s + i);
    float4 y = *(const float4*)(s + i + 4);
    bf16 t[8] = {(bf16)x.x,(bf16)x.y,(bf16)x.z,(bf16)x.w,
                 (bf16)y.x,(bf16)y.y,(bf16)y.z,(bf16)y.w};
    *(uint4*)(o + i) = *(uint4*)t;
}

// ---------------- 128x128 GEMM, global_load_lds staging ----------------
template<int MODE>
__global__ __launch_bounds__(256) void gemm128(const bf16* __restrict__ A,
                                               const bf16* __restrict__ W0,
                                               const bf16* __restrict__ W1,
                                               const bf16* __restrict__ W2,
                                               const float* __restrict__ b0,
                                               const float* __restrict__ b1,
                                               const float* __restrict__ b2,
                                               void* __restrict__ o0,
                                               void* __restrict__ o1,
                                               void* __restrict__ o2) {
    __shared__ bf16 Al[128*64];
    __shared__ bf16 Bl[128*64];
    const int t = threadIdx.x;
    const int wsel = blockIdx.x >> 3;
    const int n0 = (blockIdx.x & 7) * 128;
    const int m0 = blockIdx.y * 128;
    const bf16* W  = wsel == 0 ? W0 : wsel == 1 ? W1 : W2;
    const float* bias = wsel == 0 ? b0 : wsel == 1 ? b1 : b2;
    void* outp = wsel == 0 ? o0 : wsel == 1 ? o1 : o2;

    const int w = t >> 6, lane = t & 63, lg = lane >> 4, li = lane & 15;
    const int wr = w >> 1, wc = w & 1;
    f32x4 acc[4][4] = {};

    for (int k0 = 0; k0 < 1024; k0 += 64) {
        __syncthreads();
        #pragma unroll
        for (int i = 0; i < 4; ++i) {
            int f = i * 256 + t;            // 0..1023
            int row = f >> 3, c = (f & 7) * 8;
            GLD16(A + (size_t)(m0 + row) * 1024 + k0 + c, Al + f * 8);
            GLD16(W + (size_t)(n0 + row) * 1024 + k0 + c, Bl + f * 8);
        }
        __syncthreads();
        #pragma unroll
        for (int ks = 0; ks < 2; ++ks) {
            bf16x8 af[4], bf_[4];
            #pragma unroll
            for (int m = 0; m < 4; ++m)
                af[m] = *(const bf16x8*)&Al[(wr*64 + m*16 + li)*64 + ks*32 + lg*8];
            #pragma unroll
            for (int n = 0; n < 4; ++n)
                bf_[n] = *(const bf16x8*)&Bl[(wc*64 + n*16 + li)*64 + ks*32 + lg*8];
            #pragma unroll
            for (int m = 0; m < 4; ++m)
                #pragma unroll
                for (int n = 0; n < 4; ++n)
                    acc[m][n] = __builtin_amdgcn_mfma_f32_16x16x32_bf16(af[m], bf_[n], acc[m][n], 0,0,0);
        }
    }
    #pragma unroll
    for (int m = 0; m < 4; ++m)
      #pragma unroll
      for (int n = 0; n < 4; ++n)
        #pragma unroll
        for (int r = 0; r < 4; ++r) {
            int row = m0 + wr*64 + m*16 + lg*4 + r;
            int col = n0 + wc*64 + n*16 + li;
            float v = acc[m][n][r] + bias[col];
            if (MODE == 0) {
                int b = row >> 11, s = row & (SS-1);
                int h = col >> 6, d = col & 63;
                ((bf16*)outp)[(((size_t)(b*HH + h)*SS + s) << 6) + d] = (bf16)v;
            } else {
                ((float*)outp)[(size_t)row*1024 + col] = v;
            }
        }
}

// ---------------- V transpose: [B*H][S][64] -> [B*H][64][S] ----------------
__global__ __launch_bounds__(256) void transpose_v(const bf16* __restrict__ V,
                                                   bf16* __restrict__ Vt) {
    __shared__ bf16 L[64][72];
    const int bh = blockIdx.y, s0 = blockIdx.x * 64, t = threadIdx.x;
    for (int id = t; id < 512; id += 256) {
        int row = id >> 3, c = id & 7;
        *(uint4*)&L[row][c*8] = *(const uint4*)&V[((size_t)bh*SS + s0 + row)*64 + c*8];
    }
    __syncthreads();
    for (int id = t; id < 512; id += 256) {
        int d = id >> 3, c = id & 7;
        bf16 tmp[8];
        #pragma unroll
        for (int jj = 0; jj < 8; ++jj) tmp[jj] = L[c*8 + jj][d];
        *(uint4*)&Vt[((size_t)bh*64 + d)*SS + s0 + c*8] = *(uint4*)tmp;
    }
}

// ---------------- ALiBi attention: analytic-max folded softmax --------------
// Key identity: with m_hat(i) = slope*(S-1-i),
//   s - m_hat = qk/8 + slope*(j-(S-1))   (i-dependence cancels!)
// So exp(s - m_hat) = exp2(qk*K1 + C*(j-2047)), constants analytic & affine in j.
// Pass A: l_i = sum_j exp2(...) (K staged, double-buffered, 1 barrier/iter).
// Pass B (barrier-free): w = exp2(qk*K1 + C*(j-2047) - log2(l)) -> f32 stores,
//   bf16 copy into per-wave swizzled LDS -> PV MFMA with normalized P.
__global__ __launch_bounds__(256) void attn_kernel(const bf16* __restrict__ Q,
                                                   const bf16* __restrict__ Kk,
                                                   const bf16* __restrict__ Vt,
                                                   float* __restrict__ wout,
                                                   bf16* __restrict__ aout) {
    __shared__ bf16 Ks[2][64*64];
    __shared__ bf16 Ps[64*64];
    char* Psb = (char*)Ps;

    const int qt = blockIdx.x, bh = blockIdx.y;
    const int b = bh >> 4, h = bh & 15;
    const int q0 = qt * 64;
    const int t = threadIdx.x, w = t >> 6, lane = t & 63, lg = lane >> 4, li = lane & 15;
    const float slope = exp2f(-(float)(h + 1));
    const size_t kvbase = (size_t)bh * SS * 64;
    const size_t vtbase = (size_t)bh * 64 * SS;
    const float L2E = 1.4426950408889634f;
    const float K1 = 0.125f * L2E;
    const float C  = slope * L2E;
    const float C64 = C * 64.f;

    // Q fragment: lane li -> q row q0 + w*16 + li
    const bf16* qptr = Q + kvbase + (size_t)(q0 + w*16 + li) * 64;
    bf16x8 aq0 = *(const bf16x8*)(qptr + lg*8);
    bf16x8 aq1 = *(const bf16x8*)(qptr + 32 + lg*8);

    const int swz = (li & 7) << 4;
    float ecr[4][4];
    #pragma unroll
    for (int cb = 0; cb < 4; ++cb)
        #pragma unroll
        for (int r = 0; r < 4; ++r)
            ecr[cb][r] = C * (float)(cb*16 + lg*4 + r - (SS-1));

    float l = 0.f;

    // ---- pass A: row sums (double-buffered K staging, 1 barrier/iter) ----
    #pragma unroll
    for (int i = 0; i < 2; ++i) {
        int f = i*256 + t; int row = f >> 3, c16 = f & 7;
        GLD16(Kk + kvbase + (size_t)row*64 + (c16 ^ (row & 7))*8, &Ks[0][0] + f*8);
    }
    __syncthreads();
    for (int kt = 0; kt < 32; ++kt) {
        const int cur = kt & 1;
        if (kt + 1 < 32) {
            #pragma unroll
            for (int i = 0; i < 2; ++i) {
                int f = i*256 + t; int row = f >> 3, c16 = f & 7;
                GLD16(Kk + kvbase + (size_t)((kt+1)*64 + row)*64 + (c16 ^ (row & 7))*8,
                      &Ks[cur^1][0] + f*8);
            }
        }
        const char* Ksb = (const char*)&Ks[cur][0];
        f32x4 sc[4] = {};
        #pragma unroll
        for (int cb = 0; cb < 4; ++cb) {
            int row = cb*16 + li;
            bf16x8 bk0 = *(const bf16x8*)(Ksb + row*128 + ((     lg*16) ^ swz));
            bf16x8 bk1 = *(const bf16x8*)(Ksb + row*128 + ((64 + lg*16) ^ swz));
            sc[cb] = __builtin_amdgcn_mfma_f32_16x16x32_bf16(bk0, aq0, sc[cb], 0,0,0);
            sc[cb] = __builtin_amdgcn_mfma_f32_16x16x32_bf16(bk1, aq1, sc[cb], 0,0,0);
        }
        #pragma unroll
        for (int cb = 0; cb < 4; ++cb)
            #pragma unroll
            for (int r = 0; r < 4; ++r) {
                l += __builtin_amdgcn_exp2f(fmaf(sc[cb][r], K1, ecr[cb][r]));
                ecr[cb][r] += C64;
            }
        __syncthreads();
    }
    // combine the 4 lg-quarters of each q-row
    l += __shfl_xor(l, 16);
    l += __shfl_xor(l, 32);
    const float lgl = __builtin_amdgcn_logf(l);

    // reset exponent constants, folding -log2(l)
    #pragma unroll
    for (int cb = 0; cb < 4; ++cb)
        #pragma unroll
        for (int r = 0; r < 4; ++r)
            ecr[cb][r] = C * (float)(cb*16 + lg*4 + r - (SS-1)) - lgl;

    // ---- pass B: barrier-free weights write + PV (normalized P) ----
    f32x4 acc[4] = {};
    float* wrow = wout + ((size_t)bh*SS + q0 + w*16 + li) * SS;
    const int prow = w*16 + li;
    for (int kt = 0; kt < 32; ++kt) {
        const int j0 = kt * 64;
        const bf16* kb_ = Kk + kvbase + (size_t)j0 * 64;
        const bf16* vb_ = Vt + vtbase + j0;
        f32x4 sc[4] = {};
        #pragma unroll
        for (int cb = 0; cb < 4; ++cb) {
            const bf16* kr = kb_ + (size_t)(cb*16 + li)*64;
            bf16x8 ak0 = *(const bf16x8*)(kr + lg*8);
            bf16x8 ak1 = *(const bf16x8*)(kr + 32 + lg*8);
            sc[cb] = __builtin_amdgcn_mfma_f32_16x16x32_bf16(ak0, aq0, sc[cb], 0,0,0);
            sc[cb] = __builtin_amdgcn_mfma_f32_16x16x32_bf16(ak1, aq1, sc[cb], 0,0,0);
        }
        #pragma unroll
        for (int cb = 0; cb < 4; ++cb) {
            float4 wv;
            wv.x = __builtin_amdgcn_exp2f(fmaf(sc[cb][0], K1, ecr[cb][0]));
            wv.y = __builtin_amdgcn_exp2f(fmaf(sc[cb][1], K1, ecr[cb][1]));
            wv.z = __builtin_amdgcn_exp2f(fmaf(sc[cb][2], K1, ecr[cb][2]));
            wv.w = __builtin_amdgcn_exp2f(fmaf(sc[cb][3], K1, ecr[cb][3]));
            *(float4*)&wrow[j0 + cb*16 + lg*4] = wv;
            bf16x2 p01 = {(bf16)wv.x, (bf16)wv.y};
            bf16x2 p23 = {(bf16)wv.z, (bf16)wv.w};
            uint2 u;
            u.x = __builtin_bit_cast(unsigned, p01);
            u.y = __builtin_bit_cast(unsigned, p23);
            *(uint2*)(Psb + prow*128 + ((cb*32 + lg*8) ^ swz)) = u;
            ecr[cb][0] += C64; ecr[cb][1] += C64;
            ecr[cb][2] += C64; ecr[cb][3] += C64;
        }
        #pragma unroll
        for (int ks = 0; ks < 2; ++ks) {
            bf16x8 ap = *(const bf16x8*)(Psb + prow*128 + ((ks*64 + lg*16) ^ swz));
            #pragma unroll
            for (int d0 = 0; d0 < 4; ++d0) {
                bf16x8 bv = *(const bf16x8*)(vb_ + (size_t)(d0*16 + li)*SS + ks*32 + lg*8);
                acc[d0] = __builtin_amdgcn_mfma_f32_16x16x32_bf16(ap, bv, acc[d0], 0,0,0);
            }
        }
    }
    #pragma unroll
    for (int d0 = 0; d0 < 4; ++d0)
        #pragma unroll
        for (int r = 0; r < 4; ++r) {
            int srow = q0 + w*16 + lg*4 + r;
            aout[((size_t)(b*SS + srow))*EE + h*64 + d0*16 + li] = (bf16)acc[d0][r];
        }
}

// ---------------- launcher ----------------
extern "C" void kernel_launch(void* const* d_in, const int* in_sizes, int n_in,
                              void* d_out, int out_size, void* d_ws, size_t ws_size,
                              hipStream_t stream) {
    const float* x   = (const float*)d_in[0];
    const float* Wq  = (const float*)d_in[1];
    const float* bq  = (const float*)d_in[2];
    const float* Wk  = (const float*)d_in[3];
    const float* bk  = (const float*)d_in[4];
    const float* Wv  = (const float*)d_in[5];
    const float* bv  = (const float*)d_in[6];
    const float* Wfc = (const float*)d_in[7];
    const float* bfc = (const float*)d_in[8];

    char* ws = (char*)d_ws;
    const size_t MB = 1024u*1024u;
    bf16* xb  = (bf16*)(ws + 0);        // 8 MB
    bf16* wqb = (bf16*)(ws + 8*MB);     // 2 MB
    bf16* wkb = (bf16*)(ws + 10*MB);
    bf16* wvb = (bf16*)(ws + 12*MB);
    bf16* wfb = (bf16*)(ws + 14*MB);
    bf16* Qb  = (bf16*)(ws + 16*MB);    // 8 MB  [B*H][S][64]
    bf16* Kb  = (bf16*)(ws + 24*MB);    // 8 MB
    bf16* Vb  = (bf16*)(ws + 32*MB);    // 8 MB
    bf16* Vtb = (bf16*)(ws + 40*MB);    // 8 MB  [B*H][64][S]
    bf16* Ab  = (bf16*)(ws + 48*MB);    // 8 MB  [B][S][E]

    float* outp = (float*)d_out;
    float* wout = outp + (size_t)BB*SS*EE;

    cvt_f32_bf16<<<dim3(4194304/8/256), 256, 0, stream>>>(x, xb, 4194304);
    cvt4<<<dim3(512, 4), 256, 0, stream>>>(Wq, Wk, Wv, Wfc, wqb, wkb, wvb, wfb);

    gemm128<0><<<dim3(24, 32), 256, 0, stream>>>(xb, wqb, wkb, wvb, bq, bk, bv, Qb, Kb, Vb);

    transpose_v<<<dim3(SS/64, BB*HH), 256, 0, stream>>>(Vb, Vtb);

    attn_kernel<<<dim3(SS/64, BB*HH), 256, 0, stream>>>(Qb, Kb, Vtb, wout, Ab);

    gemm128<1><<<dim3(8, 32), 256, 0, stream>>>(Ab, wfb, wfb, wfb, bfc, bfc, bfc, d_out, d_out, d_out);
}

// Round 5
// 298.301 us; speedup vs baseline: 1.3943x; 1.3943x over previous
//
#include <hip/hip_runtime.h>
#include <hip/hip_bf16.h>
#include <cstdint>
#include <cstddef>

#define BB 2
#define SS 2048
#define EE 1024
#define HH 16
#define MM (BB*SS)   // 4096

typedef __bf16 bf16;
typedef __bf16 bf16x2 __attribute__((ext_vector_type(2)));
typedef __bf16 bf16x8 __attribute__((ext_vector_type(8)));
typedef float f32x4 __attribute__((ext_vector_type(4)));

#define GLD16(gsrc, ldst) \
  __builtin_amdgcn_global_load_lds((const __attribute__((address_space(1))) void*)(gsrc), \
                                   (__attribute__((address_space(3))) void*)(ldst), 16, 0, 0)

// ---------------- f32 -> bf16 convert ----------------
__global__ __launch_bounds__(256) void cvt_f32_bf16(const float* __restrict__ src,
                                                    bf16* __restrict__ dst, int n) {
    int i = (blockIdx.x * 256 + threadIdx.x) * 8;
    if (i >= n) return;
    float4 a = *(const float4*)(src + i);
    float4 b = *(const float4*)(src + i + 4);
    bf16 o[8] = {(bf16)a.x,(bf16)a.y,(bf16)a.z,(bf16)a.w,
                 (bf16)b.x,(bf16)b.y,(bf16)b.z,(bf16)b.w};
    *(uint4*)(dst + i) = *(uint4*)o;
}

// convert the 4 weight matrices (each 1M elems) in one launch
__global__ __launch_bounds__(256) void cvt4(const float* __restrict__ a, const float* __restrict__ b,
                                            const float* __restrict__ c, const float* __restrict__ d,
                                            bf16* __restrict__ oa, bf16* __restrict__ ob,
                                            bf16* __restrict__ oc, bf16* __restrict__ od) {
    int sel = blockIdx.y;
    const float* s = sel == 0 ? a : sel == 1 ? b : sel == 2 ? c : d;
    bf16* o       = sel == 0 ? oa : sel == 1 ? ob : sel == 2 ? oc : od;
    int i = (blockIdx.x * 256 + threadIdx.x) * 8;
    float4 x = *(const float4*)(s + i);
    float4 y = *(const float4*)(s + i + 4);
    bf16 t[8] = {(bf16)x.x,(bf16)x.y,(bf16)x.z,(bf16)x.w,
                 (bf16)y.x,(bf16)y.y,(bf16)y.z,(bf16)y.w};
    *(uint4*)(o + i) = *(uint4*)t;
}

// ---------------- 128x128 GEMM, global_load_lds staging ----------------
template<int MODE>
__global__ __launch_bounds__(256) void gemm128(const bf16* __restrict__ A,
                                               const bf16* __restrict__ W0,
                                               const bf16* __restrict__ W1,
                                               const bf16* __restrict__ W2,
                                               const float* __restrict__ b0,
                                               const float* __restrict__ b1,
                                               const float* __restrict__ b2,
                                               void* __restrict__ o0,
                                               void* __restrict__ o1,
                                               void* __restrict__ o2) {
    __shared__ bf16 Al[128*64];
    __shared__ bf16 Bl[128*64];
    const int t = threadIdx.x;
    const int wsel = blockIdx.x >> 3;
    const int n0 = (blockIdx.x & 7) * 128;
    const int m0 = blockIdx.y * 128;
    const bf16* W  = wsel == 0 ? W0 : wsel == 1 ? W1 : W2;
    const float* bias = wsel == 0 ? b0 : wsel == 1 ? b1 : b2;
    void* outp = wsel == 0 ? o0 : wsel == 1 ? o1 : o2;

    const int w = t >> 6, lane = t & 63, lg = lane >> 4, li = lane & 15;
    const int wr = w >> 1, wc = w & 1;
    f32x4 acc[4][4] = {};

    for (int k0 = 0; k0 < 1024; k0 += 64) {
        __syncthreads();
        #pragma unroll
        for (int i = 0; i < 4; ++i) {
            int f = i * 256 + t;            // 0..1023
            int row = f >> 3, c = (f & 7) * 8;
            GLD16(A + (size_t)(m0 + row) * 1024 + k0 + c, Al + f * 8);
            GLD16(W + (size_t)(n0 + row) * 1024 + k0 + c, Bl + f * 8);
        }
        __syncthreads();
        #pragma unroll
        for (int ks = 0; ks < 2; ++ks) {
            bf16x8 af[4], bf_[4];
            #pragma unroll
            for (int m = 0; m < 4; ++m)
                af[m] = *(const bf16x8*)&Al[(wr*64 + m*16 + li)*64 + ks*32 + lg*8];
            #pragma unroll
            for (int n = 0; n < 4; ++n)
                bf_[n] = *(const bf16x8*)&Bl[(wc*64 + n*16 + li)*64 + ks*32 + lg*8];
            #pragma unroll
            for (int m = 0; m < 4; ++m)
                #pragma unroll
                for (int n = 0; n < 4; ++n)
                    acc[m][n] = __builtin_amdgcn_mfma_f32_16x16x32_bf16(af[m], bf_[n], acc[m][n], 0,0,0);
        }
    }
    #pragma unroll
    for (int m = 0; m < 4; ++m)
      #pragma unroll
      for (int n = 0; n < 4; ++n)
        #pragma unroll
        for (int r = 0; r < 4; ++r) {
            int row = m0 + wr*64 + m*16 + lg*4 + r;
            int col = n0 + wc*64 + n*16 + li;
            float v = acc[m][n][r] + bias[col];
            if (MODE == 0) {
                int b = row >> 11, s = row & (SS-1);
                int h = col >> 6, d = col & 63;
                ((bf16*)outp)[(((size_t)(b*HH + h)*SS + s) << 6) + d] = (bf16)v;
            } else {
                ((float*)outp)[(size_t)row*1024 + col] = v;
            }
        }
}

// ---------------- V transpose: [B*H][S][64] -> [B*H][64][S] ----------------
__global__ __launch_bounds__(256) void transpose_v(const bf16* __restrict__ V,
                                                   bf16* __restrict__ Vt) {
    __shared__ bf16 L[64][72];
    const int bh = blockIdx.y, s0 = blockIdx.x * 64, t = threadIdx.x;
    for (int id = t; id < 512; id += 256) {
        int row = id >> 3, c = id & 7;
        *(uint4*)&L[row][c*8] = *(const uint4*)&V[((size_t)bh*SS + s0 + row)*64 + c*8];
    }
    __syncthreads();
    for (int id = t; id < 512; id += 256) {
        int d = id >> 3, c = id & 7;
        bf16 tmp[8];
        #pragma unroll
        for (int jj = 0; jj < 8; ++jj) tmp[jj] = L[c*8 + jj][d];
        *(uint4*)&Vt[((size_t)bh*64 + d)*SS + s0 + c*8] = *(uint4*)tmp;
    }
}

// ---------------- ALiBi attention: analytic-max + staged/dbuf passes -------
// Identity: with m_hat(i) = slope*(S-1-i),
//   s - m_hat = qk/8 + slope*(j-(S-1))   (i-dependence cancels).
// exp(s-m_hat) = exp2(qk*K1 + C*(j-(S-1))), constants analytic, affine in j.
// Pass A: l = sum_j exp2(...)        (K staged via GLD16, double-buffered)
// Pass B: w = exp2(... - log2 l) -> float4 stores; PV with normalized bf16 P
//         (K and V staged via GLD16, double-buffered; 1 barrier/iter)
__global__ __launch_bounds__(256) void attn_kernel(const bf16* __restrict__ Q,
                                                   const bf16* __restrict__ Kk,
                                                   const bf16* __restrict__ Vt,
                                                   float* __restrict__ wout,
                                                   bf16* __restrict__ aout) {
    __shared__ bf16 Ks[2][64*64];
    __shared__ bf16 Vs[2][64*64];
    __shared__ bf16 Ps[64*64];
    char* Psb = (char*)Ps;

    const int qt = blockIdx.x, bh = blockIdx.y;
    const int b = bh >> 4, h = bh & 15;
    const int q0 = qt * 64;
    const int t = threadIdx.x, w = t >> 6, lane = t & 63, lg = lane >> 4, li = lane & 15;
    const float slope = exp2f(-(float)(h + 1));
    const size_t kvbase = (size_t)bh * SS * 64;
    const size_t vtbase = (size_t)bh * 64 * SS;
    const float L2E = 1.4426950408889634f;
    const float K1 = 0.125f * L2E;
    const float C  = slope * L2E;
    const float C64 = C * 64.f;

    // Q fragment: lane li -> q row q0 + w*16 + li
    const bf16* qptr = Q + kvbase + (size_t)(q0 + w*16 + li) * 64;
    bf16x8 aq0 = *(const bf16x8*)(qptr + lg*8);
    bf16x8 aq1 = *(const bf16x8*)(qptr + 32 + lg*8);

    const int swz = (li & 7) << 4;
    float ecr[4][4];
    #pragma unroll
    for (int cb = 0; cb < 4; ++cb)
        #pragma unroll
        for (int r = 0; r < 4; ++r)
            ecr[cb][r] = C * (float)(cb*16 + lg*4 + r - (SS-1));

    float l = 0.f;

    // ---- pass A: row sums (double-buffered K staging, 1 barrier/iter) ----
    #pragma unroll
    for (int i = 0; i < 2; ++i) {
        int f = i*256 + t; int row = f >> 3, c16 = f & 7;
        GLD16(Kk + kvbase + (size_t)row*64 + (c16 ^ (row & 7))*8, &Ks[0][0] + f*8);
    }
    __syncthreads();
    for (int kt = 0; kt < 32; ++kt) {
        const int cur = kt & 1;
        if (kt + 1 < 32) {
            #pragma unroll
            for (int i = 0; i < 2; ++i) {
                int f = i*256 + t; int row = f >> 3, c16 = f & 7;
                GLD16(Kk + kvbase + (size_t)((kt+1)*64 + row)*64 + (c16 ^ (row & 7))*8,
                      &Ks[cur^1][0] + f*8);
            }
        }
        const char* Ksb = (const char*)&Ks[cur][0];
        f32x4 sc[4] = {};
        #pragma unroll
        for (int cb = 0; cb < 4; ++cb) {
            int row = cb*16 + li;
            bf16x8 bk0 = *(const bf16x8*)(Ksb + row*128 + ((     lg*16) ^ swz));
            bf16x8 bk1 = *(const bf16x8*)(Ksb + row*128 + ((64 + lg*16) ^ swz));
            sc[cb] = __builtin_amdgcn_mfma_f32_16x16x32_bf16(bk0, aq0, sc[cb], 0,0,0);
            sc[cb] = __builtin_amdgcn_mfma_f32_16x16x32_bf16(bk1, aq1, sc[cb], 0,0,0);
        }
        #pragma unroll
        for (int cb = 0; cb < 4; ++cb)
            #pragma unroll
            for (int r = 0; r < 4; ++r) {
                l += __builtin_amdgcn_exp2f(fmaf(sc[cb][r], K1, ecr[cb][r]));
                ecr[cb][r] += C64;
            }
        __syncthreads();
    }
    // combine the 4 lg-quarters of each q-row
    l += __shfl_xor(l, 16);
    l += __shfl_xor(l, 32);
    const float lgl = __builtin_amdgcn_logf(l);   // log2

    // reset exponent constants, folding -log2(l)
    #pragma unroll
    for (int cb = 0; cb < 4; ++cb)
        #pragma unroll
        for (int r = 0; r < 4; ++r)
            ecr[cb][r] = C * (float)(cb*16 + lg*4 + r - (SS-1)) - lgl;

    // ---- pass B: staged+dbuf K,V; weights write + PV (normalized P) ----
    f32x4 acc[4] = {};
    float* wrow = wout + ((size_t)bh*SS + q0 + w*16 + li) * SS;
    const int prow = w*16 + li;

    #pragma unroll
    for (int i = 0; i < 2; ++i) {
        int f = i*256 + t; int row = f >> 3, c16 = f & 7;
        GLD16(Kk + kvbase + (size_t)row*64 + (c16 ^ (row & 7))*8, &Ks[0][0] + f*8);
        GLD16(Vt + vtbase + (size_t)row*SS + (c16 ^ (row & 7))*8, &Vs[0][0] + f*8);
    }
    __syncthreads();
    for (int kt = 0; kt < 32; ++kt) {
        const int cur = kt & 1;
        const int j0 = kt * 64;
        if (kt + 1 < 32) {
            #pragma unroll
            for (int i = 0; i < 2; ++i) {
                int f = i*256 + t; int row = f >> 3, c16 = f & 7;
                GLD16(Kk + kvbase + (size_t)(j0 + 64 + row)*64 + (c16 ^ (row & 7))*8,
                      &Ks[cur^1][0] + f*8);
                GLD16(Vt + vtbase + (size_t)row*SS + j0 + 64 + (c16 ^ (row & 7))*8,
                      &Vs[cur^1][0] + f*8);
            }
        }
        const char* Ksb = (const char*)&Ks[cur][0];
        const char* Vsb = (const char*)&Vs[cur][0];
        f32x4 sc[4] = {};
        #pragma unroll
        for (int cb = 0; cb < 4; ++cb) {
            int row = cb*16 + li;
            bf16x8 bk0 = *(const bf16x8*)(Ksb + row*128 + ((     lg*16) ^ swz));
            bf16x8 bk1 = *(const bf16x8*)(Ksb + row*128 + ((64 + lg*16) ^ swz));
            sc[cb] = __builtin_amdgcn_mfma_f32_16x16x32_bf16(bk0, aq0, sc[cb], 0,0,0);
            sc[cb] = __builtin_amdgcn_mfma_f32_16x16x32_bf16(bk1, aq1, sc[cb], 0,0,0);
        }
        #pragma unroll
        for (int cb = 0; cb < 4; ++cb) {
            float4 wv;
            wv.x = __builtin_amdgcn_exp2f(fmaf(sc[cb][0], K1, ecr[cb][0]));
            wv.y = __builtin_amdgcn_exp2f(fmaf(sc[cb][1], K1, ecr[cb][1]));
            wv.z = __builtin_amdgcn_exp2f(fmaf(sc[cb][2], K1, ecr[cb][2]));
            wv.w = __builtin_amdgcn_exp2f(fmaf(sc[cb][3], K1, ecr[cb][3]));
            *(float4*)&wrow[j0 + cb*16 + lg*4] = wv;
            bf16x2 p01 = {(bf16)wv.x, (bf16)wv.y};
            bf16x2 p23 = {(bf16)wv.z, (bf16)wv.w};
            uint2 u;
            u.x = __builtin_bit_cast(unsigned, p01);
            u.y = __builtin_bit_cast(unsigned, p23);
            *(uint2*)(Psb + prow*128 + ((cb*32 + lg*8) ^ swz)) = u;
            ecr[cb][0] += C64; ecr[cb][1] += C64;
            ecr[cb][2] += C64; ecr[cb][3] += C64;
        }
        #pragma unroll
        for (int ks = 0; ks < 2; ++ks) {
            bf16x8 ap = *(const bf16x8*)(Psb + prow*128 + ((ks*64 + lg*16) ^ swz));
            #pragma unroll
            for (int d0 = 0; d0 < 4; ++d0) {
                int vrow = d0*16 + li;
                bf16x8 bv = *(const bf16x8*)(Vsb + vrow*128 + ((ks*64 + lg*16) ^ swz));
                acc[d0] = __builtin_amdgcn_mfma_f32_16x16x32_bf16(ap, bv, acc[d0], 0,0,0);
            }
        }
        __syncthreads();
    }
    #pragma unroll
    for (int d0 = 0; d0 < 4; ++d0)
        #pragma unroll
        for (int r = 0; r < 4; ++r) {
            int srow = q0 + w*16 + lg*4 + r;
            aout[((size_t)(b*SS + srow))*EE + h*64 + d0*16 + li] = (bf16)acc[d0][r];
        }
}

// ---------------- launcher ----------------
extern "C" void kernel_launch(void* const* d_in, const int* in_sizes, int n_in,
                              void* d_out, int out_size, void* d_ws, size_t ws_size,
                              hipStream_t stream) {
    const float* x   = (const float*)d_in[0];
    const float* Wq  = (const float*)d_in[1];
    const float* bq  = (const float*)d_in[2];
    const float* Wk  = (const float*)d_in[3];
    const float* bk  = (const float*)d_in[4];
    const float* Wv  = (const float*)d_in[5];
    const float* bv  = (const float*)d_in[6];
    const float* Wfc = (const float*)d_in[7];
    const float* bfc = (const float*)d_in[8];

    char* ws = (char*)d_ws;
    const size_t MB = 1024u*1024u;
    bf16* xb  = (bf16*)(ws + 0);        // 8 MB
    bf16* wqb = (bf16*)(ws + 8*MB);     // 2 MB
    bf16* wkb = (bf16*)(ws + 10*MB);
    bf16* wvb = (bf16*)(ws + 12*MB);
    bf16* wfb = (bf16*)(ws + 14*MB);
    bf16* Qb  = (bf16*)(ws + 16*MB);    // 8 MB  [B*H][S][64]
    bf16* Kb  = (bf16*)(ws + 24*MB);    // 8 MB
    bf16* Vb  = (bf16*)(ws + 32*MB);    // 8 MB
    bf16* Vtb = (bf16*)(ws + 40*MB);    // 8 MB  [B*H][64][S]
    bf16* Ab  = (bf16*)(ws + 48*MB);    // 8 MB  [B][S][E]

    float* outp = (float*)d_out;
    float* wout = outp + (size_t)BB*SS*EE;

    cvt_f32_bf16<<<dim3(4194304/8/256), 256, 0, stream>>>(x, xb, 4194304);
    cvt4<<<dim3(512, 4), 256, 0, stream>>>(Wq, Wk, Wv, Wfc, wqb, wkb, wvb, wfb);

    gemm128<0><<<dim3(24, 32), 256, 0, stream>>>(xb, wqb, wkb, wvb, bq, bk, bv, Qb, Kb, Vb);

    transpose_v<<<dim3(SS/64, BB*HH), 256, 0, stream>>>(Vb, Vtb);

    attn_kernel<<<dim3(SS/64, BB*HH), 256, 0, stream>>>(Qb, Kb, Vtb, wout, Ab);

    gemm128<1><<<dim3(8, 32), 256, 0, stream>>>(Ab, wfb, wfb, wfb, bfc, bfc, bfc, d_out, d_out, d_out);
}